// Round 6
// baseline (329.458 us; speedup 1.0000x reference)
//
#include <hip/hip_runtime.h>
#include <math.h>

#define N 4096
#define D 512
#define TOPK 10
#define TOPK_HALF 5
#define NT 32                            // N/128 tiles per dim
#define NCHUNK (NT * 2)                  // 64-col candidate chunks per row
#define TRI_BLOCKS (NT * (NT + 1) / 2)   // 528
#define WC_BLOCKS (N * TOPK_HALF / 4)    // 5120
#define INV_N (1.0f / 4096.0f)

typedef __bf16 bf16;
typedef __bf16 bf16x8 __attribute__((ext_vector_type(8)));
typedef float f32x4 __attribute__((ext_vector_type(4)));
typedef _Float16 f16x4 __attribute__((ext_vector_type(4)));
typedef unsigned long long u64;

__device__ __forceinline__ void gl_lds16(const void* g, void* l) {
  __builtin_amdgcn_global_load_lds(
      (const __attribute__((address_space(1))) void*)g,
      (__attribute__((address_space(3))) void*)l, 16, 0, 0);
}

// ---------------- K0: L2-normalize -> bf16 rows + rsq; also zero rowsum ----------------
__global__ __launch_bounds__(256) void k_normalize(const float* __restrict__ x,
                                                   bf16* __restrict__ y,
                                                   float* __restrict__ rowsq,
                                                   float* __restrict__ rowsum) {
  int row = blockIdx.x, tid = threadIdx.x;
  const float* xr = x + (size_t)row * D;
  float v0 = xr[tid], v1 = xr[tid + 256];
  float ss = v0 * v0 + v1 * v1;
  __shared__ float red[4];
  for (int off = 32; off > 0; off >>= 1) ss += __shfl_down(ss, off, 64);
  if ((tid & 63) == 0) red[tid >> 6] = ss;
  __syncthreads();
  float tot = red[0] + red[1] + red[2] + red[3];
  float inv = 1.0f / fmaxf(sqrtf(tot), 1e-12f);
  bf16 b0 = (bf16)(v0 * inv), b1 = (bf16)(v1 * inv);
  bf16* yr = y + (size_t)row * D;
  yr[tid] = b0; yr[tid + 256] = b1;
  float f0 = (float)b0, f1 = (float)b1;
  float s2 = f0 * f0 + f1 * f1;
  for (int off = 32; off > 0; off >>= 1) s2 += __shfl_down(s2, off, 64);
  __syncthreads();
  if ((tid & 63) == 0) red[tid >> 6] = s2;
  __syncthreads();
  if (tid == 0) {
    rowsq[row] = red[0] + red[1] + red[2] + red[3];
    rowsum[row] = 0.f;
  }
}

// ---------------- Pass 1: symmetric S-gram -> rowsum only ----------------
__global__ __launch_bounds__(256) void k_sgram_rowsum(const bf16* __restrict__ Y,
                                                      const float* __restrict__ rsq,
                                                      float* __restrict__ rowsum) {
  __shared__ bf16 As[128 * 32];
  __shared__ bf16 Bs[128 * 32];
  int t = blockIdx.x, by = 0;
  while (t >= NT - by) { t -= NT - by; ++by; }
  int bx = by + t;

  int tid = threadIdx.x;
  int lane = tid & 63, w = tid >> 6;
  int wr = w >> 1, wc = w & 1;
  f32x4 acc[4][4] = {};

  const char* Abase = (const char*)(Y + (size_t)(by * 128) * D);
  const char* Bbase = (const char*)(Y + (size_t)(bx * 128) * D);
  int c0 = tid, c1 = tid + 256;
  int r0 = c0 >> 2, q0 = c0 & 3;
  int r1 = c1 >> 2, q1 = c1 & 3;
  bf16* lA0 = As + (size_t)(w * 64) * 8;
  bf16* lA1 = As + (size_t)(256 + w * 64) * 8;
  bf16* lB0 = Bs + (size_t)(w * 64) * 8;
  bf16* lB1 = Bs + (size_t)(256 + w * 64) * 8;

  int arow = wr * 64 + (lane & 15);
  int brow = wc * 64 + (lane & 15);
  int kq = (lane >> 4) * 8;

  for (int k0 = 0; k0 < D; k0 += 32) {
    size_t off0 = (size_t)r0 * (D * 2) + (size_t)k0 * 2 + q0 * 16;
    size_t off1 = (size_t)r1 * (D * 2) + (size_t)k0 * 2 + q1 * 16;
    gl_lds16(Abase + off0, lA0);
    gl_lds16(Abase + off1, lA1);
    gl_lds16(Bbase + off0, lB0);
    gl_lds16(Bbase + off1, lB1);
    __syncthreads();
    bf16x8 af[4], bfr[4];
#pragma unroll
    for (int u = 0; u < 4; ++u) af[u] = *(bf16x8*)&As[(arow + u * 16) * 32 + kq];
#pragma unroll
    for (int v = 0; v < 4; ++v) bfr[v] = *(bf16x8*)&Bs[(brow + v * 16) * 32 + kq];
#pragma unroll
    for (int u = 0; u < 4; ++u)
#pragma unroll
      for (int v = 0; v < 4; ++v)
        acc[u][v] = __builtin_amdgcn_mfma_f32_16x16x32_bf16(af[u], bfr[v], acc[u][v], 0, 0, 0);
    __syncthreads();
  }

  int colb = bx * 128 + wc * 64 + (lane & 15);
  int rowb = by * 128 + wr * 64 + ((lane >> 4) << 2);
  float rsc[4];
#pragma unroll
  for (int v = 0; v < 4; ++v) rsc[v] = rsq[colb + v * 16];
  float cpart[4] = {0.f, 0.f, 0.f, 0.f};
#pragma unroll
  for (int u = 0; u < 4; ++u) {
    float rsr[4];
#pragma unroll
    for (int reg = 0; reg < 4; ++reg) rsr[reg] = rsq[rowb + u * 16 + reg];
    float rpart[4] = {0.f, 0.f, 0.f, 0.f};
#pragma unroll
    for (int v = 0; v < 4; ++v) {
      f32x4 a = acc[u][v];
#pragma unroll
      for (int reg = 0; reg < 4; ++reg) {
        float sq = fmaxf(rsr[reg] + rsc[v] - 2.0f * a[reg], 0.0f);
        float val = sqrtf(sq);
        rpart[reg] += val;
        cpart[v] += val;
      }
    }
#pragma unroll
    for (int reg = 0; reg < 4; ++reg) {
      float s = rpart[reg];
      s += __shfl_xor(s, 1, 64);
      s += __shfl_xor(s, 2, 64);
      s += __shfl_xor(s, 4, 64);
      s += __shfl_xor(s, 8, 64);
      if ((lane & 15) == 0) atomicAdd(&rowsum[rowb + u * 16 + reg], s);
    }
  }
  if (bx > by) {
#pragma unroll
    for (int v = 0; v < 4; ++v) {
      float s = cpart[v];
      s += __shfl_xor(s, 16, 64);
      s += __shfl_xor(s, 32, 64);
      if (lane < 16) atomicAdd(&rowsum[bx * 128 + wc * 64 + v * 16 + lane], s);
    }
  }
}

// ---------------- Pass 2: fused dual gram, register-resident epilogue ----------------
// MFMA computes D[m=j][n=i]: lane holds i = (lane&15) per v-block, 16 j's per lane.
__global__ __launch_bounds__(256) void k_fused(const bf16* __restrict__ S,
                                               const bf16* __restrict__ T,
                                               const float* __restrict__ rsq_s,
                                               const float* __restrict__ rsq_t,
                                               const float* __restrict__ rowsum,
                                               const int* __restrict__ ids,
                                               u64* __restrict__ cand,
                                               double* __restrict__ pd) {
  __shared__ bf16 Js[128 * 32];             // j-panel staging (8 KB)
  __shared__ bf16 Is[128 * 32];             // i-panel staging (8 KB)
  __shared__ u64 mbuf[4][64 * 11];          // per-wave merge buffer (22.5 KB)
  __shared__ int idsJ[128];
  __shared__ float rtJ[128], rsJ[128];

  int bx = blockIdx.x, by = blockIdx.y;
  int tid = threadIdx.x;
  int lane = tid & 63, w = tid >> 6;
  int wr = w >> 1, wc = w & 1;
  int quad = lane >> 4, c = lane & 15;

  if (tid < 128) {
    idsJ[tid] = ids[bx * 128 + tid];
    rtJ[tid] = rsq_t[bx * 128 + tid];
    rsJ[tid] = rsq_s[bx * 128 + tid];
  }

  int c0 = tid, c1 = tid + 256;
  int r0 = c0 >> 2, q0 = c0 & 3;
  int r1 = c1 >> 2, q1 = c1 & 3;
  bf16* lJ0 = Js + (size_t)(w * 64) * 8;
  bf16* lJ1 = Js + (size_t)(256 + w * 64) * 8;
  bf16* lI0 = Is + (size_t)(w * 64) * 8;
  bf16* lI1 = Is + (size_t)(256 + w * 64) * 8;

  int jrow = wr * 64 + c;     // fragment row base in Js (A-operand, m = j)
  int irow = wc * 64 + c;     // fragment row base in Is (B-operand, n = i)
  int kq = quad * 8;
  int jl_base = wr * 64;

  f32x4 acc[4][4] = {};
  // ---- T K-loop ----
  {
    const char* Jbase = (const char*)(T + (size_t)(bx * 128) * D);
    const char* Ibase = (const char*)(T + (size_t)(by * 128) * D);
    for (int k0 = 0; k0 < D; k0 += 32) {
      size_t off0 = (size_t)r0 * (D * 2) + (size_t)k0 * 2 + q0 * 16;
      size_t off1 = (size_t)r1 * (D * 2) + (size_t)k0 * 2 + q1 * 16;
      gl_lds16(Jbase + off0, lJ0);
      gl_lds16(Jbase + off1, lJ1);
      gl_lds16(Ibase + off0, lI0);
      gl_lds16(Ibase + off1, lI1);
      __syncthreads();
      bf16x8 af[4], bfr[4];
#pragma unroll
      for (int u = 0; u < 4; ++u) af[u] = *(bf16x8*)&Js[(jrow + u * 16) * 32 + kq];
#pragma unroll
      for (int v = 0; v < 4; ++v) bfr[v] = *(bf16x8*)&Is[(irow + v * 16) * 32 + kq];
#pragma unroll
      for (int u = 0; u < 4; ++u)
#pragma unroll
        for (int v = 0; v < 4; ++v)
          acc[u][v] = __builtin_amdgcn_mfma_f32_16x16x32_bf16(af[u], bfr[v], acc[u][v], 0, 0, 0);
      __syncthreads();
    }
  }

  // ---- T epilogue: per-v top-10 from registers + cross-quad merge ----
  f16x4 wph[4][4];
#pragma unroll
  for (int v = 0; v < 4; ++v) {
    int ig = by * 128 + wc * 64 + v * 16 + c;
    int idi = ids[ig];
    float rti = rsq_t[ig];
    u64 list[TOPK];
#pragma unroll
    for (int o = 0; o < TOPK; ++o) list[o] = 0ULL;
#pragma unroll
    for (int u = 0; u < 4; ++u) {
      f32x4 a = acc[u][v];
      f16x4 wpo;
#pragma unroll
      for (int reg = 0; reg < 4; ++reg) {
        int jl = jl_base + u * 16 + quad * 4 + reg;
        float tsq = fmaxf(rtJ[jl] + rti - 2.0f * a[reg], 0.0f);
        float wp = expf(-tsq);
        wpo[reg] = (_Float16)wp;
        float wkey = (idsJ[jl] == idi) ? 1.0f : wp;
        int jg = bx * 128 + jl;
        u64 key = ((u64)__float_as_uint(wkey) << 32) |
                  (u64)(0xFFFFFFFFu - (unsigned)jg);
        if (key > list[TOPK - 1]) {
          list[TOPK - 1] = key;
#pragma unroll
          for (int a2 = TOPK - 2; a2 >= 0; --a2)
            if (list[a2 + 1] > list[a2]) { u64 tt = list[a2]; list[a2] = list[a2 + 1]; list[a2 + 1] = tt; }
        }
      }
      wph[u][v] = wpo;
    }
    __syncthreads();
#pragma unroll
    for (int o = 0; o < TOPK; ++o) mbuf[w][lane * 11 + o] = list[o];
    __syncthreads();
    if (quad == 0) {
      for (int q2 = 1; q2 < 4; ++q2) {
        for (int o = 0; o < TOPK; ++o) {
          u64 key = mbuf[w][(c + q2 * 16) * 11 + o];
          if (key <= list[TOPK - 1]) break;   // sorted desc
          list[TOPK - 1] = key;
#pragma unroll
          for (int a2 = TOPK - 2; a2 >= 0; --a2)
            if (list[a2 + 1] > list[a2]) { u64 tt = list[a2]; list[a2] = list[a2 + 1]; list[a2 + 1] = tt; }
        }
      }
      u64* dst = cand + ((size_t)ig * NCHUNK + bx * 2 + wr) * TOPK;
#pragma unroll
      for (int o = 0; o < TOPK; ++o) dst[o] = list[o];
    }
  }

  // ---- S K-loop (reuse staging + acc) ----
#pragma unroll
  for (int u = 0; u < 4; ++u)
#pragma unroll
    for (int v = 0; v < 4; ++v) acc[u][v] = (f32x4){0.f, 0.f, 0.f, 0.f};
  {
    const char* Jbase = (const char*)(S + (size_t)(bx * 128) * D);
    const char* Ibase = (const char*)(S + (size_t)(by * 128) * D);
    for (int k0 = 0; k0 < D; k0 += 32) {
      size_t off0 = (size_t)r0 * (D * 2) + (size_t)k0 * 2 + q0 * 16;
      size_t off1 = (size_t)r1 * (D * 2) + (size_t)k0 * 2 + q1 * 16;
      gl_lds16(Jbase + off0, lJ0);
      gl_lds16(Jbase + off1, lJ1);
      gl_lds16(Ibase + off0, lI0);
      gl_lds16(Ibase + off1, lI1);
      __syncthreads();
      bf16x8 af[4], bfr[4];
#pragma unroll
      for (int u = 0; u < 4; ++u) af[u] = *(bf16x8*)&Js[(jrow + u * 16) * 32 + kq];
#pragma unroll
      for (int v = 0; v < 4; ++v) bfr[v] = *(bf16x8*)&Is[(irow + v * 16) * 32 + kq];
#pragma unroll
      for (int u = 0; u < 4; ++u)
#pragma unroll
        for (int v = 0; v < 4; ++v)
          acc[u][v] = __builtin_amdgcn_mfma_f32_16x16x32_bf16(af[u], bfr[v], acc[u][v], 0, 0, 0);
      __syncthreads();
    }
  }

  // ---- dense epilogue from registers ----
  float dsum = 0.f;
#pragma unroll
  for (int v = 0; v < 4; ++v) {
    int ig = by * 128 + wc * 64 + v * 16 + c;
    float meanv = rowsum[ig] * INV_N;
    float invm = 1.0f / meanv;
    float rsi = rsq_s[ig];
#pragma unroll
    for (int u = 0; u < 4; ++u) {
      f32x4 a = acc[u][v];
      f16x4 wp4 = wph[u][v];
#pragma unroll
      for (int reg = 0; reg < 4; ++reg) {
        int jl = jl_base + u * 16 + quad * 4 + reg;
        int jg = bx * 128 + jl;
        if (jg != ig) {
          float sq = fmaxf(rsJ[jl] + rsi - 2.0f * a[reg], 0.0f);
          float sdn = sqrtf(sq) * invm;
          float r = fmaxf(1.0f - sdn, 0.0f); r *= r;
          dsum += r + 0.5f * (float)wp4[reg] * (sdn * sdn - r);
        }
      }
    }
  }
  double dl = (double)dsum;
  for (int off = 32; off > 0; off >>= 1) dl += __shfl_down(dl, off, 64);
  if (lane == 0) pd[((size_t)by * NT + bx) * 4 + w] = dl;
}

// ---------------- K merge: exact global top-10 from 64 chunk lists ----------------
__global__ __launch_bounds__(256) void k_merge(const u64* __restrict__ cand,
                                               int* __restrict__ topk) {
  __shared__ u64 lists[256 * TOPK];
  int tid = threadIdx.x;
  int t = blockIdx.x * 256 + tid;
  int row = t >> 2, q = t & 3;
  const u64* src = cand + (size_t)row * (NCHUNK * TOPK) + q * (NCHUNK * TOPK / 4);
  u64 top[TOPK];
#pragma unroll
  for (int o = 0; o < TOPK; ++o) top[o] = 0ULL;
  for (int k = 0; k < NCHUNK * TOPK / 4; ++k) {
    u64 key = src[k];
    if (key > top[TOPK - 1]) {
      top[TOPK - 1] = key;
#pragma unroll
      for (int a = TOPK - 2; a >= 0; --a) {
        if (top[a + 1] > top[a]) { u64 tt = top[a]; top[a] = top[a + 1]; top[a + 1] = tt; }
      }
    }
  }
#pragma unroll
  for (int o = 0; o < TOPK; ++o) lists[tid * TOPK + o] = top[o];
  __syncthreads();
  if (q == 0) {
    for (int qq = 1; qq < 4; ++qq) {
      for (int o = 0; o < TOPK; ++o) {
        u64 key = lists[(tid + qq) * TOPK + o];
        if (key <= top[TOPK - 1]) break;
        top[TOPK - 1] = key;
#pragma unroll
        for (int a = TOPK - 2; a >= 0; --a) {
          if (top[a + 1] > top[a]) { u64 tt = top[a]; top[a] = top[a + 1]; top[a + 1] = tt; }
        }
      }
    }
#pragma unroll
    for (int o = 0; o < TOPK; ++o)
      topk[row * TOPK + o] = (int)(0xFFFFFFFFu - (unsigned)(top[o] & 0xFFFFFFFFu));
  }
}

// ---------------- K4: mutual-kNN lists ----------------
__global__ void k_buildV(const int* __restrict__ topk, int* __restrict__ L,
                         int* __restrict__ cnt) {
  int i = blockIdx.x * 256 + threadIdx.x;
  if (i >= N) return;
  int c = 0;
  for (int r = 0; r < TOPK; ++r) {
    int j = topk[i * TOPK + r];
    bool mut = false;
    for (int q = 0; q < TOPK; ++q) mut |= (topk[j * TOPK + q] == i);
    if (mut) L[i * TOPK + c++] = j;
  }
  cnt[i] = c;
}

// ---------------- K5: sparse W_C loss, one wave per task ----------------
__global__ __launch_bounds__(256) void k_wc(const int* __restrict__ topk,
                                            const int* __restrict__ L,
                                            const int* __restrict__ cnt,
                                            const bf16* __restrict__ S,
                                            const float* __restrict__ rsq,
                                            const float* __restrict__ rowsum,
                                            double* __restrict__ pw) {
  int tid = threadIdx.x;
  int lane = tid & 63;
  int wv = tid >> 6;
  int task = blockIdx.x * 4 + wv;
  int i = task / TOPK_HALF, m = task % TOPK_HALF;
  int r = topk[i * TOPK + m];
  int cr = cnt[r];
  double local = 0.0;
  if (cr > 0) {
    float denom = (float)(cr > 1 ? cr : 1);
    int lval = (lane < cr) ? L[r * TOPK + lane] : -1;
    int Lr[TOPK];
#pragma unroll
    for (int a = 0; a < TOPK; ++a) Lr[a] = __shfl(lval, a, 64);
    float invmi = 1.0f / (rowsum[i] * INV_N);
    float rsqi = rsq[i];
    bf16x8 vi = *(const bf16x8*)(S + (size_t)i * D + lane * 8);
    float fi[8];
#pragma unroll
    for (int k = 0; k < 8; ++k) fi[k] = (float)vi[k];
    int cj_l = 0; float mj_l = 1.0f;
    if (lane < cr) { cj_l = cnt[lval]; mj_l = rowsum[lval] * INV_N; }
    for (int jj = 0; jj < cr; ++jj) {
      int j = Lr[jj];
      if (j == i) continue;
      int cj = __shfl(cj_l, jj, 64);
      float mj = __shfl(mj_l, jj, 64);
      bf16x8 vj = *(const bf16x8*)(S + (size_t)j * D + lane * 8);
      float dot = 0.f;
#pragma unroll
      for (int k = 0; k < 8; ++k) dot = fmaf(fi[k], (float)vj[k], dot);
#pragma unroll
      for (int off = 32; off > 0; off >>= 1) dot += __shfl_xor(dot, off, 64);
      float sq = fmaxf(rsqi + rsq[j] - 2.0f * dot, 0.0f);
      float sr_ = sqrtf(sq);
      int ljb = (lane < cj) ? L[j * TOPK + lane] : -1;
      int match = 0;
#pragma unroll
      for (int a = 0; a < TOPK; ++a) match |= ((a < cr) && (ljb == Lr[a])) ? 1 : 0;
      int vv = __popcll(__ballot(match != 0));
      float wgt = (float)vv / denom;
      float sdij = sr_ * invmi;
      float sdji = sr_ / mj;
      float Rij = fmaxf(1.0f - sdij, 0.0f); Rij *= Rij;
      float Rji = fmaxf(1.0f - sdji, 0.0f); Rji *= Rji;
      float Fij = sdij * sdij - Rij;
      float Fji = sdji * sdji - Rji;
      local += (double)(wgt * (Fij + Fji));
    }
    local *= (1.0 / 20.0);
  }
  __shared__ double red[4];
  if (lane == 0) red[wv] = local;
  __syncthreads();
  if (tid == 0) pw[blockIdx.x] = red[0] + red[1] + red[2] + red[3];
}

// ---------------- K6: final reduce ----------------
__global__ __launch_bounds__(256) void k_final(const double* __restrict__ pd,
                                               const double* __restrict__ pw,
                                               float* __restrict__ out) {
  int tid = threadIdx.x;
  double s = 0.0;
  for (int i = tid; i < NT * NT * 4; i += 256) s += pd[i];
  for (int i = tid; i < WC_BLOCKS; i += 256) s += pw[i];
  for (int off = 32; off > 0; off >>= 1) s += __shfl_down(s, off, 64);
  __shared__ double red[4];
  if ((tid & 63) == 0) red[tid >> 6] = s;
  __syncthreads();
  if (tid == 0)
    out[0] = (float)((red[0] + red[1] + red[2] + red[3]) /
                     ((double)N * (double)(N - 1)));
}

extern "C" void kernel_launch(void* const* d_in, const int* in_sizes, int n_in,
                              void* d_out, int out_size, void* d_ws, size_t ws_size,
                              hipStream_t stream) {
  const float* s_emb = (const float*)d_in[0];
  const float* t_emb = (const float*)d_in[1];
  const int* ids = (const int*)d_in[2];
  float* out = (float*)d_out;

  char* ws = (char*)d_ws;
  size_t off = 0;
  bf16* snorm = (bf16*)(ws + off); off += (size_t)N * D * 2;        // 4 MB
  bf16* tnorm = (bf16*)(ws + off); off += (size_t)N * D * 2;        // 4 MB
  float* rsq_s = (float*)(ws + off); off += (size_t)N * 4;
  float* rsq_t = (float*)(ws + off); off += (size_t)N * 4;
  float* rowsum= (float*)(ws + off); off += (size_t)N * 4;
  int*   topk  = (int*)(ws + off);   off += (size_t)N * TOPK * 4;
  int*   L     = (int*)(ws + off);   off += (size_t)N * TOPK * 4;
  int*   cnt   = (int*)(ws + off);   off += (size_t)N * 4;
  off = (off + 15) & ~(size_t)15;
  u64*  cand   = (u64*)(ws + off);   off += (size_t)N * NCHUNK * TOPK * 8;  // 21 MB
  double* pd   = (double*)(ws + off); off += (size_t)NT * NT * 4 * 8;
  double* pw   = (double*)(ws + off); off += (size_t)WC_BLOCKS * 8;

  k_normalize<<<N, 256, 0, stream>>>(s_emb, snorm, rsq_s, rowsum);
  k_normalize<<<N, 256, 0, stream>>>(t_emb, tnorm, rsq_t, rowsum);
  k_sgram_rowsum<<<TRI_BLOCKS, 256, 0, stream>>>(snorm, rsq_s, rowsum);
  k_fused<<<dim3(NT, NT), 256, 0, stream>>>(snorm, tnorm, rsq_s, rsq_t, rowsum, ids,
                                            cand, pd);
  k_merge<<<N * 4 / 256, 256, 0, stream>>>(cand, topk);
  k_buildV<<<N / 256, 256, 0, stream>>>(topk, L, cnt);
  k_wc<<<WC_BLOCKS, 256, 0, stream>>>(topk, L, cnt, snorm, rsq_s, rowsum, pw);
  k_final<<<1, 256, 0, stream>>>(pd, pw, out);
}

// Round 7
// 292.095 us; speedup vs baseline: 1.1279x; 1.1279x over previous
//
#include <hip/hip_runtime.h>
#include <math.h>

#define N 4096
#define D 512
#define TOPK 10
#define TOPK_HALF 5
#define NT 32
#define WC_BLOCKS (N * TOPK_HALF / 4)
#define INV_N (1.0f / 4096.0f)

typedef __bf16 bf16;
typedef __bf16 bf16x8 __attribute__((ext_vector_type(8)));
typedef float f32x4 __attribute__((ext_vector_type(4)));
typedef _Float16 f16;
typedef _Float16 f16x4 __attribute__((ext_vector_type(4)));
typedef unsigned short u16;
typedef unsigned short u16x8 __attribute__((ext_vector_type(8)));
typedef unsigned int u32;
typedef unsigned long long u64;

__device__ __forceinline__ float f16tof(u16 h) {
  return (float)__builtin_bit_cast(_Float16, h);
}

// ---------------- K0: L2-normalize -> bf16 rows + rsq; zero rowsum ----------------
__global__ __launch_bounds__(256) void k_normalize(const float* __restrict__ x,
                                                   bf16* __restrict__ y,
                                                   float* __restrict__ rowsq,
                                                   float* __restrict__ rowsum) {
  int row = blockIdx.x, tid = threadIdx.x;
  const float* xr = x + (size_t)row * D;
  float v0 = xr[tid], v1 = xr[tid + 256];
  float ss = v0 * v0 + v1 * v1;
  __shared__ float red[4];
  for (int off = 32; off > 0; off >>= 1) ss += __shfl_down(ss, off, 64);
  if ((tid & 63) == 0) red[tid >> 6] = ss;
  __syncthreads();
  float tot = red[0] + red[1] + red[2] + red[3];
  float inv = 1.0f / fmaxf(sqrtf(tot), 1e-12f);
  bf16 b0 = (bf16)(v0 * inv), b1 = (bf16)(v1 * inv);
  bf16* yr = y + (size_t)row * D;
  yr[tid] = b0; yr[tid + 256] = b1;
  float f0 = (float)b0, f1 = (float)b1;
  float s2 = f0 * f0 + f1 * f1;
  for (int off = 32; off > 0; off >>= 1) s2 += __shfl_down(s2, off, 64);
  __syncthreads();
  if ((tid & 63) == 0) red[tid >> 6] = s2;
  __syncthreads();
  if (tid == 0) {
    rowsq[row] = red[0] + red[1] + red[2] + red[3];
    rowsum[row] = 0.f;
  }
}

// ---------------- Direct-fragment gram (no LDS, no barriers) ----------------
// Operand-swapped: A-panel = j rows (m=j), B-panel = i rows (n=i).
// Lane holds, per (u,v): j = bx*128 + wr*64 + u*16 + quad*4 + reg (4 consecutive),
//                        i = by*128 + wc*64 + v*16 + c.
// MODE 0: store f16 sd = sqrt(max(rsq_i+rsq_j-2dot,0)) + rowsum atomics
// MODE 1: store f16 wp = exp(-max(tsq,0))
template <int MODE>
__global__ __launch_bounds__(256) void k_dgram(const bf16* __restrict__ Y,
                                               const float* __restrict__ rsq,
                                               f16* __restrict__ G,
                                               float* __restrict__ rowsum) {
  int bx = blockIdx.x, by = blockIdx.y;
  int tid = threadIdx.x;
  int lane = tid & 63, w = tid >> 6;
  int wr = w >> 1, wc = w & 1;
  int quad = lane >> 4, c = lane & 15;

  const bf16* Jb = Y + (size_t)(bx * 128 + wr * 64 + c) * D + quad * 8;
  const bf16* Ib = Y + (size_t)(by * 128 + wc * 64 + c) * D + quad * 8;

  f32x4 acc[4][4] = {};
#pragma unroll 2
  for (int k0 = 0; k0 < D; k0 += 32) {
    bf16x8 af[4], bfr[4];
#pragma unroll
    for (int u = 0; u < 4; ++u) af[u] = *(const bf16x8*)(Jb + (size_t)(u * 16) * D + k0);
#pragma unroll
    for (int v = 0; v < 4; ++v) bfr[v] = *(const bf16x8*)(Ib + (size_t)(v * 16) * D + k0);
#pragma unroll
    for (int u = 0; u < 4; ++u)
#pragma unroll
      for (int v = 0; v < 4; ++v)
        acc[u][v] = __builtin_amdgcn_mfma_f32_16x16x32_bf16(af[u], bfr[v], acc[u][v], 0, 0, 0);
  }

#pragma unroll
  for (int v = 0; v < 4; ++v) {
    int ig = by * 128 + wc * 64 + v * 16 + c;
    float ri = rsq[ig];
    float rsv = 0.f;
#pragma unroll
    for (int u = 0; u < 4; ++u) {
      int jb0 = bx * 128 + wr * 64 + u * 16 + quad * 4;
      float4 rj = *(const float4*)(rsq + jb0);
      const float* rjp = (const float*)&rj;
      f32x4 a = acc[u][v];
      f16x4 st;
#pragma unroll
      for (int reg = 0; reg < 4; ++reg) {
        float sq = fmaxf(ri + rjp[reg] - 2.0f * a[reg], 0.0f);
        float val = (MODE == 0) ? sqrtf(sq) : expf(-sq);
        st[reg] = (_Float16)val;
        if (MODE == 0) rsv += val;
      }
      *(f16x4*)(G + (size_t)ig * N + jb0) = st;
    }
    if (MODE == 0) {
      rsv += __shfl_xor(rsv, 16, 64);
      rsv += __shfl_xor(rsv, 32, 64);
      if (lane < 16) atomicAdd(&rowsum[ig], rsv);
    }
  }
}

// ---------------- Row pass: top-10 (u32 keys) + dense loss ----------------
__global__ __launch_bounds__(256) void k_rowpass(const f16* __restrict__ Gs,
                                                 const f16* __restrict__ Gw,
                                                 const int* __restrict__ ids,
                                                 const float* __restrict__ rowsum,
                                                 int* __restrict__ topk,
                                                 double* __restrict__ pd) {
  __shared__ u32 lds[256 * TOPK];  // 10 KB
  __shared__ double dred[4];
  int i = blockIdx.x, tid = threadIdx.x;
  int idi = ids[i];
  float invm = 1.0f / (rowsum[i] * INV_N);
  const u16* srow = (const u16*)(Gs + (size_t)i * N);
  const u16* wrow = (const u16*)(Gw + (size_t)i * N);
  u32 top[TOPK];
#pragma unroll
  for (int o = 0; o < TOPK; ++o) top[o] = 0u;
  float dsum = 0.f;
  int j0 = tid * 16;
#pragma unroll
  for (int h = 0; h < 2; ++h) {
    int jb = j0 + h * 8;
    u16x8 sv = *(const u16x8*)(srow + jb);
    u16x8 wv = *(const u16x8*)(wrow + jb);
    int4 id0 = *(const int4*)(ids + jb);
    int4 id1 = *(const int4*)(ids + jb + 4);
    const int* idp = (const int*)&id0;
    const int* idp1 = (const int*)&id1;
#pragma unroll
    for (int e = 0; e < 8; ++e) {
      int j = jb + e;
      u16 hw = wv[e];
      float wp = f16tof(hw);
      if (j != i) {
        float sdn = f16tof(sv[e]) * invm;
        float r = fmaxf(1.0f - sdn, 0.0f); r *= r;
        dsum += r + 0.5f * wp * (sdn * sdn - r);
      }
      int idj = (e < 4) ? idp[e] : idp1[e - 4];
      u16 hk = (idj == idi) ? (u16)0x3C00 : hw;
      u32 key = ((u32)hk << 16) | (u32)(4095 - j);
      if (key > top[TOPK - 1]) {
        top[TOPK - 1] = key;
#pragma unroll
        for (int a = TOPK - 2; a >= 0; --a)
          if (top[a + 1] > top[a]) { u32 t = top[a]; top[a] = top[a + 1]; top[a + 1] = t; }
      }
    }
  }
  double dl = (double)dsum;
  for (int off = 32; off > 0; off >>= 1) dl += __shfl_down(dl, off, 64);
  if ((tid & 63) == 0) dred[tid >> 6] = dl;
#pragma unroll
  for (int o = 0; o < TOPK; ++o) lds[tid * TOPK + o] = top[o];
  __syncthreads();
  for (int off = 128; off >= 1; off >>= 1) {
    if (tid < off) {
      u32 out[TOPK];
      int pa = 0, pb = 0;
#pragma unroll
      for (int o = 0; o < TOPK; ++o) {
        u32 ka = lds[tid * TOPK + pa];
        u32 kb = lds[(tid + off) * TOPK + pb];
        bool ta = ka >= kb;
        out[o] = ta ? ka : kb;
        pa += ta ? 1 : 0;
        pb += ta ? 0 : 1;
      }
#pragma unroll
      for (int o = 0; o < TOPK; ++o) lds[tid * TOPK + o] = out[o];
    }
    __syncthreads();
  }
  if (tid == 0) {
#pragma unroll
    for (int o = 0; o < TOPK; ++o)
      topk[i * TOPK + o] = 4095 - (int)(lds[o] & 0xFFFu);
    pd[i] = dred[0] + dred[1] + dred[2] + dred[3];
  }
}

// ---------------- mutual-kNN lists ----------------
__global__ void k_buildV(const int* __restrict__ topk, int* __restrict__ L,
                         int* __restrict__ cnt) {
  int i = blockIdx.x * 256 + threadIdx.x;
  if (i >= N) return;
  int c = 0;
  for (int r = 0; r < TOPK; ++r) {
    int j = topk[i * TOPK + r];
    bool mut = false;
    for (int q = 0; q < TOPK; ++q) mut |= (topk[j * TOPK + q] == i);
    if (mut) L[i * TOPK + c++] = j;
  }
  cnt[i] = c;
}

// ---------------- sparse W_C loss, one wave per task ----------------
__global__ __launch_bounds__(256) void k_wc(const int* __restrict__ topk,
                                            const int* __restrict__ L,
                                            const int* __restrict__ cnt,
                                            const bf16* __restrict__ S,
                                            const float* __restrict__ rsq,
                                            const float* __restrict__ rowsum,
                                            double* __restrict__ pw) {
  int tid = threadIdx.x;
  int lane = tid & 63;
  int wv = tid >> 6;
  int task = blockIdx.x * 4 + wv;
  int i = task / TOPK_HALF, m = task % TOPK_HALF;
  int r = topk[i * TOPK + m];
  int cr = cnt[r];
  double local = 0.0;
  if (cr > 0) {
    float denom = (float)(cr > 1 ? cr : 1);
    int lval = (lane < cr) ? L[r * TOPK + lane] : -1;
    int Lr[TOPK];
#pragma unroll
    for (int a = 0; a < TOPK; ++a) Lr[a] = __shfl(lval, a, 64);
    float invmi = 1.0f / (rowsum[i] * INV_N);
    float rsqi = rsq[i];
    bf16x8 vi = *(const bf16x8*)(S + (size_t)i * D + lane * 8);
    float fi[8];
#pragma unroll
    for (int k = 0; k < 8; ++k) fi[k] = (float)vi[k];
    int cj_l = 0; float mj_l = 1.0f;
    if (lane < cr) { cj_l = cnt[lval]; mj_l = rowsum[lval] * INV_N; }
    for (int jj = 0; jj < cr; ++jj) {
      int j = Lr[jj];
      if (j == i) continue;
      int cj = __shfl(cj_l, jj, 64);
      float mj = __shfl(mj_l, jj, 64);
      bf16x8 vj = *(const bf16x8*)(S + (size_t)j * D + lane * 8);
      float dot = 0.f;
#pragma unroll
      for (int k = 0; k < 8; ++k) dot = fmaf(fi[k], (float)vj[k], dot);
#pragma unroll
      for (int off = 32; off > 0; off >>= 1) dot += __shfl_xor(dot, off, 64);
      float sq = fmaxf(rsqi + rsq[j] - 2.0f * dot, 0.0f);
      float sr_ = sqrtf(sq);
      int ljb = (lane < cj) ? L[j * TOPK + lane] : -1;
      int match = 0;
#pragma unroll
      for (int a = 0; a < TOPK; ++a) match |= ((a < cr) && (ljb == Lr[a])) ? 1 : 0;
      int vv = __popcll(__ballot(match != 0));
      float wgt = (float)vv / denom;
      float sdij = sr_ * invmi;
      float sdji = sr_ / mj;
      float Rij = fmaxf(1.0f - sdij, 0.0f); Rij *= Rij;
      float Rji = fmaxf(1.0f - sdji, 0.0f); Rji *= Rji;
      float Fij = sdij * sdij - Rij;
      float Fji = sdji * sdji - Rji;
      local += (double)(wgt * (Fij + Fji));
    }
    local *= (1.0 / 20.0);
  }
  __shared__ double red[4];
  if (lane == 0) red[wv] = local;
  __syncthreads();
  if (tid == 0) pw[blockIdx.x] = red[0] + red[1] + red[2] + red[3];
}

// ---------------- final reduce ----------------
__global__ __launch_bounds__(256) void k_final(const double* __restrict__ pd,
                                               const double* __restrict__ pw,
                                               float* __restrict__ out) {
  int tid = threadIdx.x;
  double s = 0.0;
  for (int i = tid; i < N; i += 256) s += pd[i];
  for (int i = tid; i < WC_BLOCKS; i += 256) s += pw[i];
  for (int off = 32; off > 0; off >>= 1) s += __shfl_down(s, off, 64);
  __shared__ double red[4];
  if ((tid & 63) == 0) red[tid >> 6] = s;
  __syncthreads();
  if (tid == 0)
    out[0] = (float)((red[0] + red[1] + red[2] + red[3]) /
                     ((double)N * (double)(N - 1)));
}

extern "C" void kernel_launch(void* const* d_in, const int* in_sizes, int n_in,
                              void* d_out, int out_size, void* d_ws, size_t ws_size,
                              hipStream_t stream) {
  const float* s_emb = (const float*)d_in[0];
  const float* t_emb = (const float*)d_in[1];
  const int* ids = (const int*)d_in[2];
  float* out = (float*)d_out;

  char* ws = (char*)d_ws;
  size_t off = 0;
  bf16* snorm = (bf16*)(ws + off); off += (size_t)N * D * 2;        // 4 MB
  bf16* tnorm = (bf16*)(ws + off); off += (size_t)N * D * 2;        // 4 MB
  f16*  Gsd   = (f16*)(ws + off);  off += (size_t)N * N * 2;        // 32 MB
  f16*  Gwp   = (f16*)(ws + off);  off += (size_t)N * N * 2;        // 32 MB
  float* rsq_s = (float*)(ws + off); off += (size_t)N * 4;
  float* rsq_t = (float*)(ws + off); off += (size_t)N * 4;
  float* rowsum= (float*)(ws + off); off += (size_t)N * 4;
  int*   topk  = (int*)(ws + off);   off += (size_t)N * TOPK * 4;
  int*   L     = (int*)(ws + off);   off += (size_t)N * TOPK * 4;
  int*   cnt   = (int*)(ws + off);   off += (size_t)N * 4;
  off = (off + 15) & ~(size_t)15;
  double* pd   = (double*)(ws + off); off += (size_t)N * 8;
  double* pw   = (double*)(ws + off); off += (size_t)WC_BLOCKS * 8;

  k_normalize<<<N, 256, 0, stream>>>(s_emb, snorm, rsq_s, rowsum);
  k_normalize<<<N, 256, 0, stream>>>(t_emb, tnorm, rsq_t, rowsum);
  dim3 gg(NT, NT);
  k_dgram<0><<<gg, 256, 0, stream>>>(snorm, rsq_s, Gsd, rowsum);
  k_dgram<1><<<gg, 256, 0, stream>>>(tnorm, rsq_t, Gwp, nullptr);
  k_rowpass<<<N, 256, 0, stream>>>(Gsd, Gwp, ids, rowsum, topk, pd);
  k_buildV<<<N / 256, 256, 0, stream>>>(topk, L, cnt);
  k_wc<<<WC_BLOCKS, 256, 0, stream>>>(topk, L, cnt, snorm, rsq_s, rowsum, pw);
  k_final<<<1, 256, 0, stream>>>(pd, pw, out);
}

// Round 8
// 220.208 us; speedup vs baseline: 1.4961x; 1.3264x over previous
//
#include <hip/hip_runtime.h>
#include <math.h>

#define N 4096
#define D 512
#define TOPK 10
#define TOPK_HALF 5
#define NT 32
#define WC_BLOCKS (N * TOPK_HALF / 4)
#define INV_N (1.0f / 4096.0f)

typedef __bf16 bf16;
typedef __bf16 bf16x8 __attribute__((ext_vector_type(8)));
typedef float f32x4 __attribute__((ext_vector_type(4)));
typedef _Float16 f16;
typedef _Float16 f16x4 __attribute__((ext_vector_type(4)));
typedef unsigned short u16;
typedef unsigned short u16x8 __attribute__((ext_vector_type(8)));
typedef unsigned int u32;

__device__ __forceinline__ void gl_lds16(const void* g, void* l) {
  __builtin_amdgcn_global_load_lds(
      (const __attribute__((address_space(1))) void*)g,
      (__attribute__((address_space(3))) void*)l, 16, 0, 0);
}

__device__ __forceinline__ float f16tof(u16 h) {
  return (float)__builtin_bit_cast(_Float16, h);
}

// ---------------- K0: L2-normalize -> bf16 rows + rsq; zero rowsum ----------------
__global__ __launch_bounds__(256) void k_normalize(const float* __restrict__ x,
                                                   bf16* __restrict__ y,
                                                   float* __restrict__ rowsq,
                                                   float* __restrict__ rowsum) {
  int row = blockIdx.x, tid = threadIdx.x;
  const float* xr = x + (size_t)row * D;
  float v0 = xr[tid], v1 = xr[tid + 256];
  float ss = v0 * v0 + v1 * v1;
  __shared__ float red[4];
  for (int off = 32; off > 0; off >>= 1) ss += __shfl_down(ss, off, 64);
  if ((tid & 63) == 0) red[tid >> 6] = ss;
  __syncthreads();
  float tot = red[0] + red[1] + red[2] + red[3];
  float inv = 1.0f / fmaxf(sqrtf(tot), 1e-12f);
  bf16 b0 = (bf16)(v0 * inv), b1 = (bf16)(v1 * inv);
  bf16* yr = y + (size_t)row * D;
  yr[tid] = b0; yr[tid + 256] = b1;
  float f0 = (float)b0, f1 = (float)b1;
  float s2 = f0 * f0 + f1 * f1;
  for (int off = 32; off > 0; off >>= 1) s2 += __shfl_down(s2, off, 64);
  __syncthreads();
  if ((tid & 63) == 0) red[tid >> 6] = s2;
  __syncthreads();
  if (tid == 0) {
    rowsq[row] = red[0] + red[1] + red[2] + red[3];
    rowsum[row] = 0.f;
  }
}

// ---------------- Gram: LDS-staged K-loop + slim f16 epilogue ----------------
// Operand-swapped: A-panel (Js) = j rows from bx, B-panel (Is) = i rows from by.
// acc[u][v][reg]: j = bx*128 + wr*64 + u*16 + quad*4 + reg, i = by*128 + wc*64 + v*16 + c
// MODE 0: G[i][j] = f16(sqrt(max(rsq_i+rsq_j-2dot,0))) + rowsum atomics
// MODE 1: G[i][j] = f16(exp(-max(sq,0)))
template <int MODE>
__global__ __launch_bounds__(256) void k_dgram(const bf16* __restrict__ Y,
                                               const float* __restrict__ rsq,
                                               f16* __restrict__ G,
                                               float* __restrict__ rowsum) {
  __shared__ bf16 Js[128 * 32];   // 8 KB
  __shared__ bf16 Is[128 * 32];   // 8 KB
  int bx = blockIdx.x, by = blockIdx.y;
  int tid = threadIdx.x;
  int lane = tid & 63, w = tid >> 6;
  int wr = w >> 1, wc = w & 1;
  int quad = lane >> 4, c = lane & 15;

  const char* Jbase = (const char*)(Y + (size_t)(bx * 128) * D);
  const char* Ibase = (const char*)(Y + (size_t)(by * 128) * D);
  int c0 = tid, c1 = tid + 256;
  int r0 = c0 >> 2, q0 = c0 & 3;
  int r1 = c1 >> 2, q1 = c1 & 3;
  bf16* lJ0 = Js + (size_t)(w * 64) * 8;
  bf16* lJ1 = Js + (size_t)(256 + w * 64) * 8;
  bf16* lI0 = Is + (size_t)(w * 64) * 8;
  bf16* lI1 = Is + (size_t)(256 + w * 64) * 8;

  int jrow = wr * 64 + c;
  int irow = wc * 64 + c;
  int kq = quad * 8;

  f32x4 acc[4][4] = {};
  for (int k0 = 0; k0 < D; k0 += 32) {
    size_t off0 = (size_t)r0 * (D * 2) + (size_t)k0 * 2 + q0 * 16;
    size_t off1 = (size_t)r1 * (D * 2) + (size_t)k0 * 2 + q1 * 16;
    gl_lds16(Jbase + off0, lJ0);
    gl_lds16(Jbase + off1, lJ1);
    gl_lds16(Ibase + off0, lI0);
    gl_lds16(Ibase + off1, lI1);
    __syncthreads();
    bf16x8 af[4], bfr[4];
#pragma unroll
    for (int u = 0; u < 4; ++u) af[u] = *(bf16x8*)&Js[(jrow + u * 16) * 32 + kq];
#pragma unroll
    for (int v = 0; v < 4; ++v) bfr[v] = *(bf16x8*)&Is[(irow + v * 16) * 32 + kq];
#pragma unroll
    for (int u = 0; u < 4; ++u)
#pragma unroll
      for (int v = 0; v < 4; ++v)
        acc[u][v] = __builtin_amdgcn_mfma_f32_16x16x32_bf16(af[u], bfr[v], acc[u][v], 0, 0, 0);
    __syncthreads();
  }

  // slim epilogue (R7-proven): f16x4 stores, rowsum atomics for MODE 0
#pragma unroll
  for (int v = 0; v < 4; ++v) {
    int ig = by * 128 + wc * 64 + v * 16 + c;
    float ri = rsq[ig];
    float rsv = 0.f;
#pragma unroll
    for (int u = 0; u < 4; ++u) {
      int jb0 = bx * 128 + wr * 64 + u * 16 + quad * 4;
      float4 rj = *(const float4*)(rsq + jb0);
      const float* rjp = (const float*)&rj;
      f32x4 a = acc[u][v];
      f16x4 st;
#pragma unroll
      for (int reg = 0; reg < 4; ++reg) {
        float sq = fmaxf(ri + rjp[reg] - 2.0f * a[reg], 0.0f);
        float val = (MODE == 0) ? sqrtf(sq) : expf(-sq);
        st[reg] = (_Float16)val;
        if (MODE == 0) rsv += val;
      }
      *(f16x4*)(G + (size_t)ig * N + jb0) = st;
    }
    if (MODE == 0) {
      rsv += __shfl_xor(rsv, 16, 64);
      rsv += __shfl_xor(rsv, 32, 64);
      if (lane < 16) atomicAdd(&rowsum[ig], rsv);
    }
  }
}

// ---------------- Row pass: top-10 (u32 keys) + dense loss ----------------
__global__ __launch_bounds__(256) void k_rowpass(const f16* __restrict__ Gs,
                                                 const f16* __restrict__ Gw,
                                                 const int* __restrict__ ids,
                                                 const float* __restrict__ rowsum,
                                                 int* __restrict__ topk,
                                                 double* __restrict__ pd) {
  __shared__ u32 lds[256 * TOPK];  // 10 KB
  __shared__ double dred[4];
  int i = blockIdx.x, tid = threadIdx.x;
  int idi = ids[i];
  float invm = 1.0f / (rowsum[i] * INV_N);
  const u16* srow = (const u16*)(Gs + (size_t)i * N);
  const u16* wrow = (const u16*)(Gw + (size_t)i * N);
  u32 top[TOPK];
#pragma unroll
  for (int o = 0; o < TOPK; ++o) top[o] = 0u;
  float dsum = 0.f;
  int j0 = tid * 16;
#pragma unroll
  for (int h = 0; h < 2; ++h) {
    int jb = j0 + h * 8;
    u16x8 sv = *(const u16x8*)(srow + jb);
    u16x8 wv = *(const u16x8*)(wrow + jb);
    int4 id0 = *(const int4*)(ids + jb);
    int4 id1 = *(const int4*)(ids + jb + 4);
    const int* idp = (const int*)&id0;
    const int* idp1 = (const int*)&id1;
#pragma unroll
    for (int e = 0; e < 8; ++e) {
      int j = jb + e;
      u16 hw = wv[e];
      float wp = f16tof(hw);
      if (j != i) {
        float sdn = f16tof(sv[e]) * invm;
        float r = fmaxf(1.0f - sdn, 0.0f); r *= r;
        dsum += r + 0.5f * wp * (sdn * sdn - r);
      }
      int idj = (e < 4) ? idp[e] : idp1[e - 4];
      u16 hk = (idj == idi) ? (u16)0x3C00 : hw;
      u32 key = ((u32)hk << 16) | (u32)(4095 - j);
      if (key > top[TOPK - 1]) {
        top[TOPK - 1] = key;
#pragma unroll
        for (int a = TOPK - 2; a >= 0; --a)
          if (top[a + 1] > top[a]) { u32 t = top[a]; top[a] = top[a + 1]; top[a + 1] = t; }
      }
    }
  }
  double dl = (double)dsum;
  for (int off = 32; off > 0; off >>= 1) dl += __shfl_down(dl, off, 64);
  if ((tid & 63) == 0) dred[tid >> 6] = dl;
#pragma unroll
  for (int o = 0; o < TOPK; ++o) lds[tid * TOPK + o] = top[o];
  __syncthreads();
  for (int off = 128; off >= 1; off >>= 1) {
    if (tid < off) {
      u32 out[TOPK];
      int pa = 0, pb = 0;
#pragma unroll
      for (int o = 0; o < TOPK; ++o) {
        u32 ka = lds[tid * TOPK + pa];
        u32 kb = lds[(tid + off) * TOPK + pb];
        bool ta = ka >= kb;
        out[o] = ta ? ka : kb;
        pa += ta ? 1 : 0;
        pb += ta ? 0 : 1;
      }
#pragma unroll
      for (int o = 0; o < TOPK; ++o) lds[tid * TOPK + o] = out[o];
    }
    __syncthreads();
  }
  if (tid == 0) {
#pragma unroll
    for (int o = 0; o < TOPK; ++o)
      topk[i * TOPK + o] = 4095 - (int)(lds[o] & 0xFFFu);
    pd[i] = dred[0] + dred[1] + dred[2] + dred[3];
  }
}

// ---------------- mutual-kNN lists ----------------
__global__ void k_buildV(const int* __restrict__ topk, int* __restrict__ L,
                         int* __restrict__ cnt) {
  int i = blockIdx.x * 256 + threadIdx.x;
  if (i >= N) return;
  int c = 0;
  for (int r = 0; r < TOPK; ++r) {
    int j = topk[i * TOPK + r];
    bool mut = false;
    for (int q = 0; q < TOPK; ++q) mut |= (topk[j * TOPK + q] == i);
    if (mut) L[i * TOPK + c++] = j;
  }
  cnt[i] = c;
}

// ---------------- sparse W_C loss, one wave per task ----------------
__global__ __launch_bounds__(256) void k_wc(const int* __restrict__ topk,
                                            const int* __restrict__ L,
                                            const int* __restrict__ cnt,
                                            const bf16* __restrict__ S,
                                            const float* __restrict__ rsq,
                                            const float* __restrict__ rowsum,
                                            double* __restrict__ pw) {
  int tid = threadIdx.x;
  int lane = tid & 63;
  int wv = tid >> 6;
  int task = blockIdx.x * 4 + wv;
  int i = task / TOPK_HALF, m = task % TOPK_HALF;
  int r = topk[i * TOPK + m];
  int cr = cnt[r];
  double local = 0.0;
  if (cr > 0) {
    float denom = (float)(cr > 1 ? cr : 1);
    int lval = (lane < cr) ? L[r * TOPK + lane] : -1;
    int Lr[TOPK];
#pragma unroll
    for (int a = 0; a < TOPK; ++a) Lr[a] = __shfl(lval, a, 64);
    float invmi = 1.0f / (rowsum[i] * INV_N);
    float rsqi = rsq[i];
    bf16x8 vi = *(const bf16x8*)(S + (size_t)i * D + lane * 8);
    float fi[8];
#pragma unroll
    for (int k = 0; k < 8; ++k) fi[k] = (float)vi[k];
    int cj_l = 0; float mj_l = 1.0f;
    if (lane < cr) { cj_l = cnt[lval]; mj_l = rowsum[lval] * INV_N; }
    for (int jj = 0; jj < cr; ++jj) {
      int j = Lr[jj];
      if (j == i) continue;
      int cj = __shfl(cj_l, jj, 64);
      float mj = __shfl(mj_l, jj, 64);
      bf16x8 vj = *(const bf16x8*)(S + (size_t)j * D + lane * 8);
      float dot = 0.f;
#pragma unroll
      for (int k = 0; k < 8; ++k) dot = fmaf(fi[k], (float)vj[k], dot);
#pragma unroll
      for (int off = 32; off > 0; off >>= 1) dot += __shfl_xor(dot, off, 64);
      float sq = fmaxf(rsqi + rsq[j] - 2.0f * dot, 0.0f);
      float sr_ = sqrtf(sq);
      int ljb = (lane < cj) ? L[j * TOPK + lane] : -1;
      int match = 0;
#pragma unroll
      for (int a = 0; a < TOPK; ++a) match |= ((a < cr) && (ljb == Lr[a])) ? 1 : 0;
      int vv = __popcll(__ballot(match != 0));
      float wgt = (float)vv / denom;
      float sdij = sr_ * invmi;
      float sdji = sr_ / mj;
      float Rij = fmaxf(1.0f - sdij, 0.0f); Rij *= Rij;
      float Rji = fmaxf(1.0f - sdji, 0.0f); Rji *= Rji;
      float Fij = sdij * sdij - Rij;
      float Fji = sdji * sdji - Rji;
      local += (double)(wgt * (Fij + Fji));
    }
    local *= (1.0 / 20.0);
  }
  __shared__ double red[4];
  if (lane == 0) red[wv] = local;
  __syncthreads();
  if (tid == 0) pw[blockIdx.x] = red[0] + red[1] + red[2] + red[3];
}

// ---------------- final reduce ----------------
__global__ __launch_bounds__(256) void k_final(const double* __restrict__ pd,
                                               const double* __restrict__ pw,
                                               float* __restrict__ out) {
  int tid = threadIdx.x;
  double s = 0.0;
  for (int i = tid; i < N; i += 256) s += pd[i];
  for (int i = tid; i < WC_BLOCKS; i += 256) s += pw[i];
  for (int off = 32; off > 0; off >>= 1) s += __shfl_down(s, off, 64);
  __shared__ double red[4];
  if ((tid & 63) == 0) red[tid >> 6] = s;
  __syncthreads();
  if (tid == 0)
    out[0] = (float)((red[0] + red[1] + red[2] + red[3]) /
                     ((double)N * (double)(N - 1)));
}

extern "C" void kernel_launch(void* const* d_in, const int* in_sizes, int n_in,
                              void* d_out, int out_size, void* d_ws, size_t ws_size,
                              hipStream_t stream) {
  const float* s_emb = (const float*)d_in[0];
  const float* t_emb = (const float*)d_in[1];
  const int* ids = (const int*)d_in[2];
  float* out = (float*)d_out;

  char* ws = (char*)d_ws;
  size_t off = 0;
  bf16* snorm = (bf16*)(ws + off); off += (size_t)N * D * 2;        // 4 MB
  bf16* tnorm = (bf16*)(ws + off); off += (size_t)N * D * 2;        // 4 MB
  f16*  Gsd   = (f16*)(ws + off);  off += (size_t)N * N * 2;        // 32 MB
  f16*  Gwp   = (f16*)(ws + off);  off += (size_t)N * N * 2;        // 32 MB
  float* rsq_s = (float*)(ws + off); off += (size_t)N * 4;
  float* rsq_t = (float*)(ws + off); off += (size_t)N * 4;
  float* rowsum= (float*)(ws + off); off += (size_t)N * 4;
  int*   topk  = (int*)(ws + off);   off += (size_t)N * TOPK * 4;
  int*   L     = (int*)(ws + off);   off += (size_t)N * TOPK * 4;
  int*   cnt   = (int*)(ws + off);   off += (size_t)N * 4;
  off = (off + 15) & ~(size_t)15;
  double* pd   = (double*)(ws + off); off += (size_t)N * 8;
  double* pw   = (double*)(ws + off); off += (size_t)WC_BLOCKS * 8;

  k_normalize<<<N, 256, 0, stream>>>(s_emb, snorm, rsq_s, rowsum);
  k_normalize<<<N, 256, 0, stream>>>(t_emb, tnorm, rsq_t, rowsum);
  dim3 gg(NT, NT);
  k_dgram<0><<<gg, 256, 0, stream>>>(snorm, rsq_s, Gsd, rowsum);
  k_dgram<1><<<gg, 256, 0, stream>>>(tnorm, rsq_t, Gwp, nullptr);
  k_rowpass<<<N, 256, 0, stream>>>(Gsd, Gwp, ids, rowsum, topk, pd);
  k_buildV<<<N / 256, 256, 0, stream>>>(topk, L, cnt);
  k_wc<<<WC_BLOCKS, 256, 0, stream>>>(topk, L, cnt, snorm, rsq_s, rowsum, pw);
  k_final<<<1, 256, 0, stream>>>(pd, pw, out);
}

// Round 9
// 211.232 us; speedup vs baseline: 1.5597x; 1.0425x over previous
//
#include <hip/hip_runtime.h>
#include <math.h>

#define N 4096
#define D 512
#define TOPK 10
#define TOPK_HALF 5
#define NT 32
#define WC_BLOCKS (N * TOPK_HALF / 4)
#define INV_N (1.0f / 4096.0f)

typedef __bf16 bf16;
typedef __bf16 bf16x8 __attribute__((ext_vector_type(8)));
typedef float f32x4 __attribute__((ext_vector_type(4)));
typedef _Float16 f16;
typedef _Float16 f16x4 __attribute__((ext_vector_type(4)));
typedef unsigned short u16;
typedef unsigned short u16x8 __attribute__((ext_vector_type(8)));
typedef unsigned int u32;

__device__ __forceinline__ void gl_lds16(const void* g, void* l) {
  __builtin_amdgcn_global_load_lds(
      (const __attribute__((address_space(1))) void*)g,
      (__attribute__((address_space(3))) void*)l, 16, 0, 0);
}

__device__ __forceinline__ float f16tof(u16 h) {
  return (float)__builtin_bit_cast(_Float16, h);
}

// ---------------- K0: L2-normalize both matrices (z = blockIdx>>12) ----------------
__global__ __launch_bounds__(256) void k_normalize2(const float* __restrict__ xs,
                                                    const float* __restrict__ xt,
                                                    bf16* __restrict__ ys,
                                                    bf16* __restrict__ yt,
                                                    float* __restrict__ rsq_s,
                                                    float* __restrict__ rsq_t,
                                                    float* __restrict__ rowsum) {
  int b = blockIdx.x;
  int row = b & (N - 1);
  int is_t = b >> 12;
  const float* x = is_t ? xt : xs;
  bf16* y = is_t ? yt : ys;
  float* rowsq = is_t ? rsq_t : rsq_s;
  int tid = threadIdx.x;
  const float* xr = x + (size_t)row * D;
  float v0 = xr[tid], v1 = xr[tid + 256];
  float ss = v0 * v0 + v1 * v1;
  __shared__ float red[4];
  for (int off = 32; off > 0; off >>= 1) ss += __shfl_down(ss, off, 64);
  if ((tid & 63) == 0) red[tid >> 6] = ss;
  __syncthreads();
  float tot = red[0] + red[1] + red[2] + red[3];
  float inv = 1.0f / fmaxf(sqrtf(tot), 1e-12f);
  bf16 b0 = (bf16)(v0 * inv), b1 = (bf16)(v1 * inv);
  bf16* yr = y + (size_t)row * D;
  yr[tid] = b0; yr[tid + 256] = b1;
  float f0 = (float)b0, f1 = (float)b1;
  float s2 = f0 * f0 + f1 * f1;
  for (int off = 32; off > 0; off >>= 1) s2 += __shfl_down(s2, off, 64);
  __syncthreads();
  if ((tid & 63) == 0) red[tid >> 6] = s2;
  __syncthreads();
  if (tid == 0) {
    rowsq[row] = red[0] + red[1] + red[2] + red[3];
    if (!is_t) rowsum[row] = 0.f;
  }
}

// ---------------- Gram: BK=64 double-buffered K-loop + slim f16 epilogue ----------------
// blockIdx.z: 0 = S-gram (sd + rowsum), 1 = T-gram (wp). Operand-swapped:
// acc[u][v][reg]: j = bx*128 + wr*64 + u*16 + quad*4 + reg, i = by*128 + wc*64 + v*16 + c
__global__ __launch_bounds__(256) void k_dgram2(const bf16* __restrict__ S,
                                                const bf16* __restrict__ T,
                                                const float* __restrict__ rsq_s,
                                                const float* __restrict__ rsq_t,
                                                f16* __restrict__ Gsd,
                                                f16* __restrict__ Gwp,
                                                float* __restrict__ rowsum) {
  __shared__ bf16 Jb0[128 * 32];   // 8 KB each, [row][32] layout (bank-safe, gl_lds-contiguous)
  __shared__ bf16 Jb1[128 * 32];
  __shared__ bf16 Ib0[128 * 32];
  __shared__ bf16 Ib1[128 * 32];
  int bx = blockIdx.x, by = blockIdx.y, z = blockIdx.z;
  const bf16* Y = z ? T : S;
  const float* rsq = z ? rsq_t : rsq_s;
  f16* G = z ? Gwp : Gsd;

  int tid = threadIdx.x;
  int lane = tid & 63, w = tid >> 6;
  int wr = w >> 1, wc = w & 1;
  int quad = lane >> 4, c = lane & 15;

  const char* Jbase = (const char*)(Y + (size_t)(bx * 128) * D);
  const char* Ibase = (const char*)(Y + (size_t)(by * 128) * D);
  // chunk c: row = c>>2, q = c&3 (16B per chunk, 64B per buffer row)
  int r0 = tid >> 2, q0 = tid & 3;
  int r1 = (tid + 256) >> 2, q1 = (tid + 256) & 3;
  size_t so0 = (size_t)r0 * (D * 2) + q0 * 16;
  size_t so1 = (size_t)r1 * (D * 2) + q1 * 16;
  // wave-uniform LDS bases (HW adds lane*16)
  bf16* lJ0a = Jb0 + (size_t)w * 512;  bf16* lJ0b = Jb0 + (size_t)(256 + w * 64) * 8;
  bf16* lJ1a = Jb1 + (size_t)w * 512;  bf16* lJ1b = Jb1 + (size_t)(256 + w * 64) * 8;
  bf16* lI0a = Ib0 + (size_t)w * 512;  bf16* lI0b = Ib0 + (size_t)(256 + w * 64) * 8;
  bf16* lI1a = Ib1 + (size_t)w * 512;  bf16* lI1b = Ib1 + (size_t)(256 + w * 64) * 8;

  int jrow = wr * 64 + c;
  int irow = wc * 64 + c;
  int kq = quad * 8;

  f32x4 acc[4][4] = {};
  for (int k0 = 0; k0 < D; k0 += 64) {
    size_t kb = (size_t)k0 * 2;
    gl_lds16(Jbase + so0 + kb,      lJ0a);
    gl_lds16(Jbase + so1 + kb,      lJ0b);
    gl_lds16(Jbase + so0 + kb + 64, lJ1a);
    gl_lds16(Jbase + so1 + kb + 64, lJ1b);
    gl_lds16(Ibase + so0 + kb,      lI0a);
    gl_lds16(Ibase + so1 + kb,      lI0b);
    gl_lds16(Ibase + so0 + kb + 64, lI1a);
    gl_lds16(Ibase + so1 + kb + 64, lI1b);
    __syncthreads();
    {
      bf16x8 af[4], bfr[4];
#pragma unroll
      for (int u = 0; u < 4; ++u) af[u] = *(bf16x8*)&Jb0[(jrow + u * 16) * 32 + kq];
#pragma unroll
      for (int v = 0; v < 4; ++v) bfr[v] = *(bf16x8*)&Ib0[(irow + v * 16) * 32 + kq];
#pragma unroll
      for (int u = 0; u < 4; ++u)
#pragma unroll
        for (int v = 0; v < 4; ++v)
          acc[u][v] = __builtin_amdgcn_mfma_f32_16x16x32_bf16(af[u], bfr[v], acc[u][v], 0, 0, 0);
    }
    {
      bf16x8 af[4], bfr[4];
#pragma unroll
      for (int u = 0; u < 4; ++u) af[u] = *(bf16x8*)&Jb1[(jrow + u * 16) * 32 + kq];
#pragma unroll
      for (int v = 0; v < 4; ++v) bfr[v] = *(bf16x8*)&Ib1[(irow + v * 16) * 32 + kq];
#pragma unroll
      for (int u = 0; u < 4; ++u)
#pragma unroll
        for (int v = 0; v < 4; ++v)
          acc[u][v] = __builtin_amdgcn_mfma_f32_16x16x32_bf16(af[u], bfr[v], acc[u][v], 0, 0, 0);
    }
    __syncthreads();
  }

  // slim epilogue (R7/R8-proven)
#pragma unroll
  for (int v = 0; v < 4; ++v) {
    int ig = by * 128 + wc * 64 + v * 16 + c;
    float ri = rsq[ig];
    float rsv = 0.f;
#pragma unroll
    for (int u = 0; u < 4; ++u) {
      int jb0i = bx * 128 + wr * 64 + u * 16 + quad * 4;
      float4 rj = *(const float4*)(rsq + jb0i);
      const float* rjp = (const float*)&rj;
      f32x4 a = acc[u][v];
      f16x4 st;
      if (z == 0) {
#pragma unroll
        for (int reg = 0; reg < 4; ++reg) {
          float sq = fmaxf(ri + rjp[reg] - 2.0f * a[reg], 0.0f);
          float val = sqrtf(sq);
          st[reg] = (_Float16)val;
          rsv += val;
        }
      } else {
#pragma unroll
        for (int reg = 0; reg < 4; ++reg) {
          float sq = fmaxf(ri + rjp[reg] - 2.0f * a[reg], 0.0f);
          st[reg] = (_Float16)expf(-sq);
        }
      }
      *(f16x4*)(G + (size_t)ig * N + jb0i) = st;
    }
    if (z == 0) {
      rsv += __shfl_xor(rsv, 16, 64);
      rsv += __shfl_xor(rsv, 32, 64);
      if (lane < 16) atomicAdd(&rowsum[ig], rsv);
    }
  }
}

// ---------------- Row pass: top-10 (u32 keys) + dense loss ----------------
__global__ __launch_bounds__(256) void k_rowpass(const f16* __restrict__ Gs,
                                                 const f16* __restrict__ Gw,
                                                 const int* __restrict__ ids,
                                                 const float* __restrict__ rowsum,
                                                 int* __restrict__ topk,
                                                 double* __restrict__ pd) {
  __shared__ u32 lds[256 * TOPK];  // 10 KB
  __shared__ double dred[4];
  int i = blockIdx.x, tid = threadIdx.x;
  int idi = ids[i];
  float invm = 1.0f / (rowsum[i] * INV_N);
  const u16* srow = (const u16*)(Gs + (size_t)i * N);
  const u16* wrow = (const u16*)(Gw + (size_t)i * N);
  u32 top[TOPK];
#pragma unroll
  for (int o = 0; o < TOPK; ++o) top[o] = 0u;
  float dsum = 0.f;
  int j0 = tid * 16;
#pragma unroll
  for (int h = 0; h < 2; ++h) {
    int jb = j0 + h * 8;
    u16x8 sv = *(const u16x8*)(srow + jb);
    u16x8 wv = *(const u16x8*)(wrow + jb);
    int4 id0 = *(const int4*)(ids + jb);
    int4 id1 = *(const int4*)(ids + jb + 4);
    const int* idp = (const int*)&id0;
    const int* idp1 = (const int*)&id1;
#pragma unroll
    for (int e = 0; e < 8; ++e) {
      int j = jb + e;
      u16 hw = wv[e];
      float wp = f16tof(hw);
      if (j != i) {
        float sdn = f16tof(sv[e]) * invm;
        float r = fmaxf(1.0f - sdn, 0.0f); r *= r;
        dsum += r + 0.5f * wp * (sdn * sdn - r);
      }
      int idj = (e < 4) ? idp[e] : idp1[e - 4];
      u16 hk = (idj == idi) ? (u16)0x3C00 : hw;
      u32 key = ((u32)hk << 16) | (u32)(4095 - j);
      if (key > top[TOPK - 1]) {
        top[TOPK - 1] = key;
#pragma unroll
        for (int a = TOPK - 2; a >= 0; --a)
          if (top[a + 1] > top[a]) { u32 t = top[a]; top[a] = top[a + 1]; top[a + 1] = t; }
      }
    }
  }
  double dl = (double)dsum;
  for (int off = 32; off > 0; off >>= 1) dl += __shfl_down(dl, off, 64);
  if ((tid & 63) == 0) dred[tid >> 6] = dl;
#pragma unroll
  for (int o = 0; o < TOPK; ++o) lds[tid * TOPK + o] = top[o];
  __syncthreads();
  for (int off = 128; off >= 1; off >>= 1) {
    if (tid < off) {
      u32 out[TOPK];
      int pa = 0, pb = 0;
#pragma unroll
      for (int o = 0; o < TOPK; ++o) {
        u32 ka = lds[tid * TOPK + pa];
        u32 kb = lds[(tid + off) * TOPK + pb];
        bool ta = ka >= kb;
        out[o] = ta ? ka : kb;
        pa += ta ? 1 : 0;
        pb += ta ? 0 : 1;
      }
#pragma unroll
      for (int o = 0; o < TOPK; ++o) lds[tid * TOPK + o] = out[o];
    }
    __syncthreads();
  }
  if (tid == 0) {
#pragma unroll
    for (int o = 0; o < TOPK; ++o)
      topk[i * TOPK + o] = 4095 - (int)(lds[o] & 0xFFFu);
    pd[i] = dred[0] + dred[1] + dred[2] + dred[3];
  }
}

// ---------------- mutual-kNN lists ----------------
__global__ void k_buildV(const int* __restrict__ topk, int* __restrict__ L,
                         int* __restrict__ cnt) {
  int i = blockIdx.x * 256 + threadIdx.x;
  if (i >= N) return;
  int c = 0;
  for (int r = 0; r < TOPK; ++r) {
    int j = topk[i * TOPK + r];
    bool mut = false;
    for (int q = 0; q < TOPK; ++q) mut |= (topk[j * TOPK + q] == i);
    if (mut) L[i * TOPK + c++] = j;
  }
  cnt[i] = c;
}

// ---------------- sparse W_C loss, one wave per task ----------------
__global__ __launch_bounds__(256) void k_wc(const int* __restrict__ topk,
                                            const int* __restrict__ L,
                                            const int* __restrict__ cnt,
                                            const bf16* __restrict__ S,
                                            const float* __restrict__ rsq,
                                            const float* __restrict__ rowsum,
                                            double* __restrict__ pw) {
  int tid = threadIdx.x;
  int lane = tid & 63;
  int wv = tid >> 6;
  int task = blockIdx.x * 4 + wv;
  int i = task / TOPK_HALF, m = task % TOPK_HALF;
  int r = topk[i * TOPK + m];
  int cr = cnt[r];
  double local = 0.0;
  if (cr > 0) {
    float denom = (float)(cr > 1 ? cr : 1);
    int lval = (lane < cr) ? L[r * TOPK + lane] : -1;
    int Lr[TOPK];
#pragma unroll
    for (int a = 0; a < TOPK; ++a) Lr[a] = __shfl(lval, a, 64);
    float invmi = 1.0f / (rowsum[i] * INV_N);
    float rsqi = rsq[i];
    bf16x8 vi = *(const bf16x8*)(S + (size_t)i * D + lane * 8);
    float fi[8];
#pragma unroll
    for (int k = 0; k < 8; ++k) fi[k] = (float)vi[k];
    int cj_l = 0; float mj_l = 1.0f;
    if (lane < cr) { cj_l = cnt[lval]; mj_l = rowsum[lval] * INV_N; }
    for (int jj = 0; jj < cr; ++jj) {
      int j = Lr[jj];
      if (j == i) continue;
      int cj = __shfl(cj_l, jj, 64);
      float mj = __shfl(mj_l, jj, 64);
      bf16x8 vj = *(const bf16x8*)(S + (size_t)j * D + lane * 8);
      float dot = 0.f;
#pragma unroll
      for (int k = 0; k < 8; ++k) dot = fmaf(fi[k], (float)vj[k], dot);
#pragma unroll
      for (int off = 32; off > 0; off >>= 1) dot += __shfl_xor(dot, off, 64);
      float sq = fmaxf(rsqi + rsq[j] - 2.0f * dot, 0.0f);
      float sr_ = sqrtf(sq);
      int ljb = (lane < cj) ? L[j * TOPK + lane] : -1;
      int match = 0;
#pragma unroll
      for (int a = 0; a < TOPK; ++a) match |= ((a < cr) && (ljb == Lr[a])) ? 1 : 0;
      int vv = __popcll(__ballot(match != 0));
      float wgt = (float)vv / denom;
      float sdij = sr_ * invmi;
      float sdji = sr_ / mj;
      float Rij = fmaxf(1.0f - sdij, 0.0f); Rij *= Rij;
      float Rji = fmaxf(1.0f - sdji, 0.0f); Rji *= Rji;
      float Fij = sdij * sdij - Rij;
      float Fji = sdji * sdji - Rji;
      local += (double)(wgt * (Fij + Fji));
    }
    local *= (1.0 / 20.0);
  }
  __shared__ double red[4];
  if (lane == 0) red[wv] = local;
  __syncthreads();
  if (tid == 0) pw[blockIdx.x] = red[0] + red[1] + red[2] + red[3];
}

// ---------------- final reduce ----------------
__global__ __launch_bounds__(256) void k_final(const double* __restrict__ pd,
                                               const double* __restrict__ pw,
                                               float* __restrict__ out) {
  int tid = threadIdx.x;
  double s = 0.0;
  for (int i = tid; i < N; i += 256) s += pd[i];
  for (int i = tid; i < WC_BLOCKS; i += 256) s += pw[i];
  for (int off = 32; off > 0; off >>= 1) s += __shfl_down(s, off, 64);
  __shared__ double red[4];
  if ((tid & 63) == 0) red[tid >> 6] = s;
  __syncthreads();
  if (tid == 0)
    out[0] = (float)((red[0] + red[1] + red[2] + red[3]) /
                     ((double)N * (double)(N - 1)));
}

extern "C" void kernel_launch(void* const* d_in, const int* in_sizes, int n_in,
                              void* d_out, int out_size, void* d_ws, size_t ws_size,
                              hipStream_t stream) {
  const float* s_emb = (const float*)d_in[0];
  const float* t_emb = (const float*)d_in[1];
  const int* ids = (const int*)d_in[2];
  float* out = (float*)d_out;

  char* ws = (char*)d_ws;
  size_t off = 0;
  bf16* snorm = (bf16*)(ws + off); off += (size_t)N * D * 2;        // 4 MB
  bf16* tnorm = (bf16*)(ws + off); off += (size_t)N * D * 2;        // 4 MB
  f16*  Gsd   = (f16*)(ws + off);  off += (size_t)N * N * 2;        // 32 MB
  f16*  Gwp   = (f16*)(ws + off);  off += (size_t)N * N * 2;        // 32 MB
  float* rsq_s = (float*)(ws + off); off += (size_t)N * 4;
  float* rsq_t = (float*)(ws + off); off += (size_t)N * 4;
  float* rowsum= (float*)(ws + off); off += (size_t)N * 4;
  int*   topk  = (int*)(ws + off);   off += (size_t)N * TOPK * 4;
  int*   L     = (int*)(ws + off);   off += (size_t)N * TOPK * 4;
  int*   cnt   = (int*)(ws + off);   off += (size_t)N * 4;
  off = (off + 15) & ~(size_t)15;
  double* pd   = (double*)(ws + off); off += (size_t)N * 8;
  double* pw   = (double*)(ws + off); off += (size_t)WC_BLOCKS * 8;

  k_normalize2<<<2 * N, 256, 0, stream>>>(s_emb, t_emb, snorm, tnorm,
                                          rsq_s, rsq_t, rowsum);
  k_dgram2<<<dim3(NT, NT, 2), 256, 0, stream>>>(snorm, tnorm, rsq_s, rsq_t,
                                                Gsd, Gwp, rowsum);
  k_rowpass<<<N, 256, 0, stream>>>(Gsd, Gwp, ids, rowsum, topk, pd);
  k_buildV<<<N / 256, 256, 0, stream>>>(topk, L, cnt);
  k_wc<<<WC_BLOCKS, 256, 0, stream>>>(topk, L, cnt, snorm, rsq_s, rowsum, pw);
  k_final<<<1, 256, 0, stream>>>(pd, pw, out);
}